// Round 10
// baseline (101.993 us; speedup 1.0000x reference)
//
#include <hip/hip_runtime.h>
#include <math.h>

#define N_ROWS 16384
#define D_INP  1024
#define D_LAT  128
#define KC     256
#define EPS_F  1e-8f
#define NBLK   1280

typedef _Float16 half8v __attribute__((ext_vector_type(8))); // 8 fp16
typedef __attribute__((ext_vector_type(4))) float floatx4;   // mfma C/D
typedef __attribute__((ext_vector_type(4))) float f4v;

__device__ __forceinline__ unsigned short f2h(float f) {
    _Float16 h = (_Float16)f;
    unsigned short u;
    __builtin_memcpy(&u, &h, 2);
    return u;
}
__device__ __forceinline__ float h2f(unsigned short u) {
    _Float16 h;
    __builtin_memcpy(&h, &u, 2);
    return (float)h;
}

// ---------------------------------------------------------------------------
// Single fused kernel, 1280 blocks x 512 threads.
//   bid%5==0 : cluster block (cid=bid/5, 64 rows). Reads R fp32 from L2
//              directly (no prep kernel): A/B MFMA fragments converted
//              in-register, r2 computed via shfl over g-groups.
//   else     : recon block (rid), register-batched nt float4 stream.
// Last-arriving block (device atomic counter) reduces all partials in a
// FIXED order and writes out[0] — deterministic, no separate finalize.
// ---------------------------------------------------------------------------
__global__ __launch_bounds__(512) void mono_kernel(
        const float* __restrict__ x, const float* __restrict__ a,
        const float* __restrict__ h, const float* __restrict__ R,
        float* __restrict__ pr, float* __restrict__ pc,
        unsigned* __restrict__ counter, float* __restrict__ out) {
    __shared__ unsigned short sh16[64 * 136];  // h fp16, row stride 136 (17.4 KB)
    __shared__ unsigned short eL[64 * 264];    // e fp16, row stride 264 (33.8 KB)
    __shared__ float sumsL[64][16];            // 4 KB
    __shared__ float r2L[KC];                  // 1 KB
    __shared__ float h2L[64];
    __shared__ float invL[64];
    __shared__ float swL[8];
    __shared__ int lastFlag;

    const int bid = blockIdx.x;
    const int tid = threadIdx.x;
    const int wv = tid >> 6, lane = tid & 63;

    if (bid % 5 != 0) {
        // ---------------- recon ----------------
        const int rid = bid - 1 - bid / 5;               // 0..1023
        const int gid = rid * 512 + tid;
        const f4v* x4 = (const f4v*)x;
        const f4v* a4 = (const f4v*)a;
        f4v xv[8], av[8];
#pragma unroll
        for (int it = 0; it < 8; ++it) {
            const int i = gid + it * (512 * 1024);
            xv[it] = __builtin_nontemporal_load(x4 + i);
            av[it] = __builtin_nontemporal_load(a4 + i);
        }
        float a0 = 0.f, a1 = 0.f, a2 = 0.f, a3 = 0.f;
#pragma unroll
        for (int it = 0; it < 8; ++it) {
            const float d0 = xv[it].x - av[it].x, d1 = xv[it].y - av[it].y;
            const float d2 = xv[it].z - av[it].z, d3 = xv[it].w - av[it].w;
            a0 = fmaf(d0, d0, a0);
            a1 = fmaf(d1, d1, a1);
            a2 = fmaf(d2, d2, a2);
            a3 = fmaf(d3, d3, a3);
        }
        float acc = (a0 + a1) + (a2 + a3);
        for (int off = 32; off > 0; off >>= 1) acc += __shfl_down(acc, off);
        if (lane == 0) swL[wv] = acc;
        __syncthreads();
        if (tid == 0) {
            float t = 0.f;
#pragma unroll
            for (int w = 0; w < 8; ++w) t += swL[w];
            pr[rid] = t;
        }
    } else {
        // ---------------- cluster ----------------
        const int cid = bid / 5;                 // 0..255
        const int rbase = cid * 64;
        const int g = lane >> 4, c = lane & 15;

        // stage h (64 rows x 128): fp16 convert + per-row |h|^2.
        {
            const int r = tid >> 3, c8 = tid & 7;
            const float* hrow = h + (size_t)(rbase + r) * D_LAT;
            float s = 0.f;
#pragma unroll
            for (int q = 0; q < 4; ++q) {
                const int c4 = c8 + q * 8;
                const f4v v = __builtin_nontemporal_load((const f4v*)(hrow + c4 * 4));
                sh16[r * 136 + c4 * 4 + 0] = f2h(v.x);
                sh16[r * 136 + c4 * 4 + 1] = f2h(v.y);
                sh16[r * 136 + c4 * 4 + 2] = f2h(v.z);
                sh16[r * 136 + c4 * 4 + 3] = f2h(v.w);
                s = fmaf(v.x, v.x, s);
                s = fmaf(v.y, v.y, s);
                s = fmaf(v.z, v.z, s);
                s = fmaf(v.w, v.w, s);
            }
            s += __shfl_xor(s, 1);
            s += __shfl_xor(s, 2);
            s += __shfl_xor(s, 4);
            if ((tid & 7) == 0) h2L[r] = s;
        }

        // load A-operand B-fragments (R row-major) fp32 -> fp16 regs + r2.
        half8v bA[2][4];
#pragma unroll
        for (int tt = 0; tt < 2; ++tt) {
            const int kc = (wv * 2 + tt) * 16 + c;
            float s = 0.f;
#pragma unroll
            for (int ks = 0; ks < 4; ++ks) {
                const float* rp = R + (size_t)kc * D_LAT + ks * 32 + g * 8;
                const f4v p0 = *(const f4v*)rp;
                const f4v p1 = *(const f4v*)(rp + 4);
                half8v b;
                b[0] = (_Float16)p0.x; b[1] = (_Float16)p0.y;
                b[2] = (_Float16)p0.z; b[3] = (_Float16)p0.w;
                b[4] = (_Float16)p1.x; b[5] = (_Float16)p1.y;
                b[6] = (_Float16)p1.z; b[7] = (_Float16)p1.w;
                bA[tt][ks] = b;
                s = fmaf(p0.x, p0.x, s); s = fmaf(p0.y, p0.y, s);
                s = fmaf(p0.z, p0.z, s); s = fmaf(p0.w, p0.w, s);
                s = fmaf(p1.x, p1.x, s); s = fmaf(p1.y, p1.y, s);
                s = fmaf(p1.z, p1.z, s); s = fmaf(p1.w, p1.w, s);
            }
            s += __shfl_xor(s, 16);
            s += __shfl_xor(s, 32);
            if (g == 0) r2L[kc] = s;
        }
        __syncthreads();

        // ---- phase A: S = h.R^T (fp16 mfma), B-frags reused across 4 row-tiles ----
        {
            const float r2v[2] = {r2L[wv * 32 + c], r2L[wv * 32 + 16 + c]};
#pragma unroll
            for (int rt = 0; rt < 4; ++rt) {
                half8v aH[4];
#pragma unroll
                for (int ks = 0; ks < 4; ++ks)
                    aH[ks] = *(const half8v*)&sh16[(rt * 16 + c) * 136 + ks * 32 + g * 8];
                float h2a[4];
#pragma unroll
                for (int i = 0; i < 4; ++i) h2a[i] = h2L[rt * 16 + 4 * g + i];
#pragma unroll
                for (int tt = 0; tt < 2; ++tt) {
                    floatx4 acc = {0.f, 0.f, 0.f, 0.f};
#pragma unroll
                    for (int ks = 0; ks < 4; ++ks)
                        acc = __builtin_amdgcn_mfma_f32_16x16x32_f16(aH[ks], bA[tt][ks], acc, 0, 0, 0);
                    const int kc = (wv * 2 + tt) * 16 + c;
#pragma unroll
                    for (int i = 0; i < 4; ++i) {
                        const float d2 = h2a[i] + r2v[tt] - 2.0f * acc[i];
                        const float e = __expf(-sqrtf(fmaxf(d2, 0.f)));
                        eL[(rt * 16 + 4 * g + i) * 264 + kc] = f2h(e);
                        float v = e;
                        v += __shfl_xor(v, 1);
                        v += __shfl_xor(v, 2);
                        v += __shfl_xor(v, 4);
                        v += __shfl_xor(v, 8);
                        if (c == 0) sumsL[rt * 16 + 4 * g + i][wv * 2 + tt] = v;
                    }
                }
            }
        }
        __syncthreads();
        if (tid < 64) {
            float t = 0.f;
#pragma unroll
            for (int j = 0; j < 16; ++j) t += sumsL[tid][j];
            invL[tid] = 1.0f / (t + EPS_F);
        }
        __syncthreads();

        // ---- phase B: wc = E.R (fp16 mfma), R^T frags from fp32 R ----
        {
            const int dcol = wv * 16 + c;
            half8v bB[8];
#pragma unroll
            for (int ks = 0; ks < 8; ++ks) {
                const int kb = ks * 32 + g * 8;
                half8v b;
#pragma unroll
                for (int j = 0; j < 8; ++j)
                    b[j] = (_Float16)R[(size_t)(kb + j) * D_LAT + dcol];
                bB[ks] = b;
            }
            float lp = 0.f;
#pragma unroll
            for (int rt = 0; rt < 4; ++rt) {
                floatx4 acc = {0.f, 0.f, 0.f, 0.f};
#pragma unroll
                for (int ks = 0; ks < 8; ++ks) {
                    const half8v ae = *(const half8v*)&eL[(rt * 16 + c) * 264 + ks * 32 + g * 8];
                    acc = __builtin_amdgcn_mfma_f32_16x16x32_f16(ae, bB[ks], acc, 0, 0, 0);
                }
#pragma unroll
                for (int i = 0; i < 4; ++i) {
                    const int row = rt * 16 + 4 * g + i;
                    const float wc = acc[i] * invL[row];
                    const float hv = h2f(sh16[row * 136 + dcol]);
                    const float df = hv - wc;
                    lp = fmaf(df, df, lp);
                }
            }
            for (int off = 32; off > 0; off >>= 1) lp += __shfl_down(lp, off);
            if (lane == 0) swL[wv] = lp;
        }
        __syncthreads();
        if (tid == 0) {
            float t = 0.f;
#pragma unroll
            for (int w = 0; w < 8; ++w) t += swL[w];
            pc[cid] = t;
        }
    }

    // ---------------- last-block finalize (deterministic fixed-order) -------
    if (tid == 0) {
        __threadfence();
        lastFlag = (atomicAdd(counter, 1u) == NBLK - 1);
    }
    __syncthreads();
    if (lastFlag) {
        __threadfence();
        float aa = 0.f, bb = 0.f;
        for (int i = tid; i < 1024; i += 512) aa += pr[i];   // fixed 2-term order
        if (tid < 256) bb = pc[tid];
        float v = aa * (1.0f / ((float)N_ROWS * (float)D_INP)) +
                  bb * (1.0f / ((float)N_ROWS * (float)D_LAT));
        for (int off = 32; off > 0; off >>= 1) v += __shfl_down(v, off);
        __syncthreads();                      // swL free for reuse
        if (lane == 0) swL[wv] = v;
        __syncthreads();
        if (tid == 0) {
            float t = 0.f;
#pragma unroll
            for (int w = 0; w < 8; ++w) t += swL[w];
            out[0] = t;
        }
    }
}

extern "C" void kernel_launch(void* const* d_in, const int* in_sizes, int n_in,
                              void* d_out, int out_size, void* d_ws, size_t ws_size,
                              hipStream_t stream) {
    const float* x = (const float*)d_in[0];
    const float* h = (const float*)d_in[1];
    const float* a = (const float*)d_in[2];
    const float* R = (const float*)d_in[3];
    float* out = (float*)d_out;
    char* wsb = (char*)d_ws;
    float* pr = (float*)(wsb + 0);            // 1024 f
    float* pc = (float*)(wsb + 4096);         // 256 f
    unsigned* counter = (unsigned*)(wsb + 8192);

    hipMemsetAsync(counter, 0, 4, stream);
    mono_kernel<<<NBLK, 512, 0, stream>>>(x, a, h, R, pr, pc, counter, out);
}